// Round 17
// baseline (283.724 us; speedup 1.0000x reference)
//
#include <hip/hip_runtime.h>
#include <hip/hip_bf16.h>
#include <cmath>

#define NN 100000
#define NE 1600000
#define NBATCH 64
#define NB 391        // buckets of 256 nodes (dst>>8)
#define NBP 512       // padded bucket count
#define BCAP 5120     // fixed bucket capacity (mean 4096, sigma ~64 -> +16 sigma)
#define NPAD (NB * BCAP)

typedef __attribute__((ext_vector_type(8))) _Float16 f16x8;
typedef __attribute__((ext_vector_type(4))) float f32x4;
typedef __attribute__((ext_vector_type(2))) float f32x2;

__device__ __forceinline__ void atomAdd(float* p, float v) {
  unsafeAtomicAdd(p, v);
}

__device__ __forceinline__ unsigned char f2fp8(float f) {
  int pk = __builtin_amdgcn_cvt_pk_fp8_f32(f, f, 0, false);
  return (unsigned char)(pk & 0xff);
}

__device__ __forceinline__ void acc8_init(f32x2* acc, uint4 v) {
  acc[0] = __builtin_amdgcn_cvt_pk_f32_fp8(v.x, false);
  acc[1] = __builtin_amdgcn_cvt_pk_f32_fp8(v.x, true);
  acc[2] = __builtin_amdgcn_cvt_pk_f32_fp8(v.y, false);
  acc[3] = __builtin_amdgcn_cvt_pk_f32_fp8(v.y, true);
  acc[4] = __builtin_amdgcn_cvt_pk_f32_fp8(v.z, false);
  acc[5] = __builtin_amdgcn_cvt_pk_f32_fp8(v.z, true);
  acc[6] = __builtin_amdgcn_cvt_pk_f32_fp8(v.w, false);
  acc[7] = __builtin_amdgcn_cvt_pk_f32_fp8(v.w, true);
}
__device__ __forceinline__ void acc8_add(f32x2* acc, uint4 v) {
  acc[0] += __builtin_amdgcn_cvt_pk_f32_fp8(v.x, false);
  acc[1] += __builtin_amdgcn_cvt_pk_f32_fp8(v.x, true);
  acc[2] += __builtin_amdgcn_cvt_pk_f32_fp8(v.y, false);
  acc[3] += __builtin_amdgcn_cvt_pk_f32_fp8(v.y, true);
  acc[4] += __builtin_amdgcn_cvt_pk_f32_fp8(v.z, false);
  acc[5] += __builtin_amdgcn_cvt_pk_f32_fp8(v.z, true);
  acc[6] += __builtin_amdgcn_cvt_pk_f32_fp8(v.w, false);
  acc[7] += __builtin_amdgcn_cvt_pk_f32_fp8(v.w, true);
}

// ---- bin edges into fixed-capacity bucket regions (LDS counting sort / 4096-chunk) ----
__global__ __launch_bounds__(256) void k_bin(const int* __restrict__ src,
    const int* __restrict__ dst, int* __restrict__ bucketCnt, unsigned* __restrict__ pairs,
    const float* __restrict__ W2, const float* __restrict__ W3, const float* __restrict__ W4,
    _Float16* __restrict__ Wt2, _Float16* __restrict__ Wt3, _Float16* __restrict__ Wt4) {
  __shared__ int hist[NBP];
  __shared__ int scn[NBP];
  __shared__ int ofs[NBP];
  __shared__ int gbase[NBP];
  __shared__ unsigned buf[4096];
  __shared__ unsigned short bufb[4096];
  const int base = blockIdx.x * 4096;
  const int n = (NE - base < 4096) ? NE - base : 4096;
  for (int i = threadIdx.x; i < NBP; i += 256) hist[i] = 0;
  __syncthreads();

  int myS[16], myD[16];
  int nloc = 0;
  for (int i = threadIdx.x, j = 0; i < n; i += 256, ++j) {
    myS[j] = src[base + i];
    myD[j] = dst[base + i];
    atomicAdd(&hist[myD[j] >> 8], 1);
    nloc = j + 1;
  }
  __syncthreads();

  scn[threadIdx.x] = hist[threadIdx.x];
  scn[threadIdx.x + 256] = hist[threadIdx.x + 256];
  __syncthreads();
  for (int off = 1; off < NBP; off <<= 1) {
    const int i0 = threadIdx.x, i1 = threadIdx.x + 256;
    int t0 = (i0 >= off) ? scn[i0 - off] : 0;
    int t1 = (i1 >= off) ? scn[i1 - off] : 0;
    __syncthreads();
    scn[i0] += t0;
    scn[i1] += t1;
    __syncthreads();
  }
  ofs[threadIdx.x] = scn[threadIdx.x] - hist[threadIdx.x];
  ofs[threadIdx.x + 256] = scn[threadIdx.x + 256] - hist[threadIdx.x + 256];
  for (int b = threadIdx.x; b < NB; b += 256) {
    int c = hist[b];
    if (c) gbase[b] = b * BCAP + atomicAdd(&bucketCnt[b], c);
  }
  __syncthreads();

  for (int j = 0; j < nloc; ++j) {
    int b = myD[j] >> 8;
    int slot = atomicAdd(&ofs[b], 1);
    buf[slot] = ((unsigned)myS[j] << 8) | ((unsigned)myD[j] & 255u);
    bufb[slot] = (unsigned short)b;
  }
  __syncthreads();

  for (int i = threadIdx.x; i < n; i += 256) {
    int b = (int)bufb[i];
    int ex = scn[b] - hist[b];
    pairs[gbase[b] + (i - ex)] = buf[i];
  }

  int idx = blockIdx.x * 256 + threadIdx.x;
  if (idx < 2048) {
    int k = idx / 64, m = idx - k * 64;
    Wt2[m * 32 + k] = (_Float16)W2[idx];
  } else if (idx < 10240) {
    int j = idx - 2048;
    int k = j / 128, m = j - k * 128;
    Wt3[m * 64 + k] = (_Float16)W3[j];
  } else if (idx < 43008) {
    int j = idx - 10240;
    int k = j / 256, m = j - k * 256;
    Wt4[m * 128 + k] = (_Float16)W4[j];
  }
}

// ---- per-bucket: count + local scan -> rowbeg/rowend/dinv + csrc fill + batch hist + xs8 pack ----
__global__ __launch_bounds__(256) void k_cntfill(const unsigned* __restrict__ pairs,
    const int* __restrict__ bucketCnt, const int* __restrict__ batch,
    const float* __restrict__ x, int* __restrict__ rowbeg, int* __restrict__ rowend,
    float* __restrict__ dinv, int* __restrict__ csrc, float* __restrict__ pcnt,
    _Float16* __restrict__ xs8) {
  __shared__ int c[256];
  __shared__ int scn[256];
  __shared__ int rowb[256];
  __shared__ int ofs[256];
  __shared__ int h[64];
  const int tid = threadIdx.x;
  c[tid] = 0; ofs[tid] = 0;
  if (tid < 64) h[tid] = 0;
  __syncthreads();
  const int b = blockIdx.x;
  const int s = b * BCAP;
  const int e = s + bucketCnt[b];
  for (int i = s + tid; i < e; i += 256) atomicAdd(&c[pairs[i] & 255u], 1);
  __syncthreads();
  const int v = c[tid];
  scn[tid] = v;
  __syncthreads();
  for (int off = 1; off < 256; off <<= 1) {
    int t = (tid >= off) ? scn[tid - off] : 0;
    __syncthreads();
    scn[tid] += t;
    __syncthreads();
  }
  rowb[tid] = s + scn[tid] - v;
  const int node = b * 256 + tid;
  rowbeg[node] = rowb[tid];
  rowend[node] = rowb[tid] + v;
  if (node < NN) {
    const float di = rsqrtf((float)v + 1.0f);
    dinv[node] = di;
    f16x8 o = {0, 0, 0, 0, 0, 0, 0, 0};
    o[0] = (_Float16)(x[(size_t)node * 5 + 0] * di);
    o[1] = (_Float16)(x[(size_t)node * 5 + 1] * di);
    o[2] = (_Float16)(x[(size_t)node * 5 + 2] * di);
    o[3] = (_Float16)(x[(size_t)node * 5 + 3] * di);
    o[4] = (_Float16)(x[(size_t)node * 5 + 4] * di);
    *(f16x8*)(xs8 + (size_t)node * 8) = o;
    atomicAdd(&h[batch[node]], 1);
  }
  __syncthreads();
  for (int i = s + tid; i < e; i += 256) {
    unsigned p = pairs[i];
    int t = (int)(p & 255u);
    int pos = rowb[t] + atomicAdd(&ofs[t], 1);
    csrc[pos] = (int)(p >> 8);
  }
  if (tid < 64 && h[tid]) atomAdd(&pcnt[tid], (float)h[tid]);
}

// ================== phase args ==================
struct MegaArgs {
  const _Float16* xs8;
  const int* rowbeg; const int* rowend; const int* csrc;
  const float* dinv;
  const float* W1; const float* b1;
  unsigned char* F0;
  const _Float16* Wt2; const float* b2;
  unsigned char* F1;
  const _Float16* Wt3; const float* b3;
  unsigned char* F2;
  const _Float16* Wt4; const float* b4;
  unsigned char* AG8;
  const int* batch; float* pooled; const float* pcnt;
  const float* fc1w; const float* fc1b; const float* fc2w; const float* fc2b;
  float* out;
};

// ---- layer1: fp16 xs8 gather + 5->32 GEMM, fp8 out (pre-scaled) ----
__global__ __launch_bounds__(256) void kw_l1(MegaArgs a) {
  __shared__ float w_s[160];
  __shared__ float b_s[32];
  const int tid = threadIdx.x;
  if (tid < 160) w_s[tid] = a.W1[tid];
  if (tid < 32) b_s[tid] = a.b1[tid];
  __syncthreads();
  const int r = blockIdx.x * 256 + tid;
  if (r >= NN) return;
  const float di = a.dinv[r];
  f16x8 av = *(const f16x8*)(a.xs8 + (size_t)r * 8);
  f16x8 cacc = {0, 0, 0, 0, 0, 0, 0, 0};
  int e = a.rowbeg[r];
  const int e1 = a.rowend[r];
  for (; e + 2 <= e1; e += 2) {
    const int s0 = a.csrc[e], s1 = a.csrc[e + 1];
    av   += *(const f16x8*)(a.xs8 + (size_t)s0 * 8);
    cacc += *(const f16x8*)(a.xs8 + (size_t)s1 * 8);
  }
  if (e < e1) av += *(const f16x8*)(a.xs8 + (size_t)a.csrc[e] * 8);
  av += cacc;
  const float f0 = (float)av[0] * di, f1 = (float)av[1] * di, f2 = (float)av[2] * di,
              f3 = (float)av[3] * di, f4 = (float)av[4] * di;
  float v[32];
#pragma unroll
  for (int j = 0; j < 32; ++j) {
    float s = b_s[j] + f0 * w_s[j] + f1 * w_s[32 + j] + f2 * w_s[64 + j]
                     + f3 * w_s[96 + j] + f4 * w_s[128 + j];
    v[j] = fmaxf(s, 0.f) * di;
  }
  unsigned u[8];
#pragma unroll
  for (int g2 = 0; g2 < 8; ++g2) {
    int uu = 0;
    uu = __builtin_amdgcn_cvt_pk_fp8_f32(v[4 * g2],     v[4 * g2 + 1], uu, false);
    uu = __builtin_amdgcn_cvt_pk_fp8_f32(v[4 * g2 + 2], v[4 * g2 + 3], uu, true);
    u[g2] = (unsigned)uu;
  }
  uint4* op = (uint4*)(a.F0 + (size_t)r * 32);
  op[0] = make_uint4(u[0], u[1], u[2], u[3]);
  op[1] = make_uint4(u[4], u[5], u[6], u[7]);
}

// ---- FUSED small-K layer: fp8 gather -> fp16 LDS -> MFMA GEMM -> fp8 out (pre-scaled) ----
// One gather pass: TPR = K/16 lanes per row (16B fp8 each), 64*TPR <= 256 threads active.
template<int K, int M>
__global__ __launch_bounds__(256) void kw_fused(const unsigned char* __restrict__ in,
    MegaArgs a, const _Float16* __restrict__ Wt, const float* __restrict__ bias,
    unsigned char* __restrict__ outp) {
  constexpr int KC = 32;
  constexpr int KP = K + 8;
  constexpr int WP = KC + 8;
  constexpr int CTW = M / 64;
  constexpr int TPR = K / 16;
  __shared__ _Float16 a_s[64 * KP];
  __shared__ _Float16 w_s[M * WP];
  const int tid = threadIdx.x;
  const int r0 = blockIdx.x * 64;

  // ---- gather phase (single pass, into LDS) ----
  {
    const int lr = tid / TPR;
    const int c = (tid % TPR) * 16;
    if (lr < 64) {
      const int r = r0 + lr;
      _Float16 h[16];
      if (r < NN) {
        const float di = a.dinv[r];
        f32x2 acc[8];
        acc8_init(acc, *(const uint4*)(in + (size_t)r * K + c));
        int e = a.rowbeg[r];
        const int e1 = a.rowend[r];
        for (; e + 2 <= e1; e += 2) {
          const int s0 = a.csrc[e], s1 = a.csrc[e + 1];
          const uint4 v0 = *(const uint4*)(in + (size_t)s0 * K + c);
          const uint4 v1 = *(const uint4*)(in + (size_t)s1 * K + c);
          acc8_add(acc, v0);
          acc8_add(acc, v1);
        }
        if (e < e1) acc8_add(acc, *(const uint4*)(in + (size_t)a.csrc[e] * K + c));
#pragma unroll
        for (int j = 0; j < 8; ++j) {
          h[2 * j]     = (_Float16)(acc[j].x * di);
          h[2 * j + 1] = (_Float16)(acc[j].y * di);
        }
      } else {
#pragma unroll
        for (int j = 0; j < 16; ++j) h[j] = (_Float16)0.f;
      }
      *(uint4*)&a_s[lr * KP + c]     = *(uint4*)&h[0];
      *(uint4*)&a_s[lr * KP + c + 8] = *(uint4*)&h[8];
    }
  }

  // ---- GEMM phase (first __syncthreads in the loop makes a_s visible) ----
  const int wave = tid >> 6, lane = tid & 63;
  const int m16 = lane & 15, q = lane >> 4;
  f32x4 acc[4][CTW];
#pragma unroll
  for (int rt = 0; rt < 4; ++rt)
#pragma unroll
    for (int ct = 0; ct < CTW; ++ct) acc[rt][ct] = (f32x4){0.f, 0.f, 0.f, 0.f};

  for (int kc = 0; kc < K; kc += KC) {
    __syncthreads();
    for (int idx = tid; idx < M * (KC / 8); idx += 256) {
      int m = idx / (KC / 8), cc = (idx % (KC / 8)) * 8;
      uint4 v = *(const uint4*)(Wt + (size_t)m * K + kc + cc);
      *(uint4*)&w_s[m * WP + cc] = v;
    }
    __syncthreads();
    f16x8 bfr[CTW];
#pragma unroll
    for (int ct = 0; ct < CTW; ++ct)
      bfr[ct] = *(const f16x8*)&w_s[(wave * (M / 4) + ct * 16 + m16) * WP + q * 8];
#pragma unroll
    for (int rt = 0; rt < 4; ++rt) {
      f16x8 afr = *(const f16x8*)&a_s[(rt * 16 + m16) * KP + kc + q * 8];
#pragma unroll
      for (int ct = 0; ct < CTW; ++ct)
        acc[rt][ct] = __builtin_amdgcn_mfma_f32_16x16x32_f16(afr, bfr[ct], acc[rt][ct], 0, 0, 0);
    }
  }

  float dsc[4][4];
#pragma unroll
  for (int rt = 0; rt < 4; ++rt)
#pragma unroll
    for (int reg = 0; reg < 4; ++reg) {
      const int row = r0 + rt * 16 + q * 4 + reg;
      dsc[rt][reg] = (row < NN) ? a.dinv[row] : 0.f;
    }
#pragma unroll
  for (int rt = 0; rt < 4; ++rt) {
#pragma unroll
    for (int ct = 0; ct < CTW; ++ct) {
      const int col = wave * (M / 4) + ct * 16 + m16;
      const float bv = bias[col];
#pragma unroll
      for (int reg = 0; reg < 4; ++reg) {
        const int row = r0 + rt * 16 + q * 4 + reg;
        if (row < NN) {
          float vv = fmaxf(acc[rt][ct][reg] + bv, 0.f) * dsc[rt][reg];
          outp[(size_t)row * M + col] = f2fp8(vv);
        }
      }
    }
  }
}

// ---- fp8 CSR gather (K=128) -> fp8 AG (pre-scaled); blocks 0..63 also zero pooled ----
__global__ __launch_bounds__(256) void kw_gather128(const unsigned char* __restrict__ in,
    MegaArgs a) {
  constexpr int K = 128;
  constexpr int TPR = 8;
  constexpr int RPB = 32;
  if (blockIdx.x < 64) a.pooled[blockIdx.x * 256 + threadIdx.x] = 0.f;
  const int r = blockIdx.x * RPB + threadIdx.x / TPR;
  if (r >= NN) return;
  const int c = (threadIdx.x % TPR) * 16;
  const float di = a.dinv[r];
  f32x2 acc[8];
  acc8_init(acc, *(const uint4*)(in + (size_t)r * K + c));
  int e = a.rowbeg[r];
  const int e1 = a.rowend[r];
  for (; e + 2 <= e1; e += 2) {
    const int s0 = a.csrc[e], s1 = a.csrc[e + 1];
    const uint4 v0 = *(const uint4*)(in + (size_t)s0 * K + c);
    const uint4 v1 = *(const uint4*)(in + (size_t)s1 * K + c);
    acc8_add(acc, v0);
    acc8_add(acc, v1);
  }
  if (e < e1) acc8_add(acc, *(const uint4*)(in + (size_t)a.csrc[e] * K + c));
  int w0, w1, w2, w3;
  w0 = __builtin_amdgcn_cvt_pk_fp8_f32(acc[0].x * di, acc[0].y * di, 0, false);
  w0 = __builtin_amdgcn_cvt_pk_fp8_f32(acc[1].x * di, acc[1].y * di, w0, true);
  w1 = __builtin_amdgcn_cvt_pk_fp8_f32(acc[2].x * di, acc[2].y * di, 0, false);
  w1 = __builtin_amdgcn_cvt_pk_fp8_f32(acc[3].x * di, acc[3].y * di, w1, true);
  w2 = __builtin_amdgcn_cvt_pk_fp8_f32(acc[4].x * di, acc[4].y * di, 0, false);
  w2 = __builtin_amdgcn_cvt_pk_fp8_f32(acc[5].x * di, acc[5].y * di, w2, true);
  w3 = __builtin_amdgcn_cvt_pk_fp8_f32(acc[6].x * di, acc[6].y * di, 0, false);
  w3 = __builtin_amdgcn_cvt_pk_fp8_f32(acc[7].x * di, acc[7].y * di, w3, true);
  *(uint4*)(a.AG8 + (size_t)r * K + c) = make_uint4((unsigned)w0, (unsigned)w1,
                                                    (unsigned)w2, (unsigned)w3);
}

// ---- layer-4 MFMA GEMM (fp8 AG staged to fp16 LDS) + fused mean-pool ----
__global__ __launch_bounds__(256) void kw_gemm4(MegaArgs a,
    const _Float16* __restrict__ Wt, const float* __restrict__ bias) {
  constexpr int K = 128, M = 256;
  constexpr int KC = 32;
  constexpr int KP = K + 8;
  constexpr int WP = KC + 8;
  constexpr int CTW = M / 64;
  constexpr int C16 = K / 16;
  __shared__ _Float16 a_s[64 * KP];
  __shared__ _Float16 w_s[M * WP];
  const int tid = threadIdx.x;
  const int wave = tid >> 6, lane = tid & 63;
  const int m16 = lane & 15, q = lane >> 4;
  const int r0 = blockIdx.x * 64;

  for (int idx = tid; idx < 64 * C16; idx += 256) {
    int row = idx / C16, cc = (idx % C16) * 16;
    uint4 v = {0u, 0u, 0u, 0u};
    if (r0 + row < NN) v = *(const uint4*)(a.AG8 + (size_t)(r0 + row) * K + cc);
    f32x2 t;
    _Float16 h[16];
    t = __builtin_amdgcn_cvt_pk_f32_fp8(v.x, false); h[0] = (_Float16)t.x;  h[1] = (_Float16)t.y;
    t = __builtin_amdgcn_cvt_pk_f32_fp8(v.x, true);  h[2] = (_Float16)t.x;  h[3] = (_Float16)t.y;
    t = __builtin_amdgcn_cvt_pk_f32_fp8(v.y, false); h[4] = (_Float16)t.x;  h[5] = (_Float16)t.y;
    t = __builtin_amdgcn_cvt_pk_f32_fp8(v.y, true);  h[6] = (_Float16)t.x;  h[7] = (_Float16)t.y;
    t = __builtin_amdgcn_cvt_pk_f32_fp8(v.z, false); h[8] = (_Float16)t.x;  h[9] = (_Float16)t.y;
    t = __builtin_amdgcn_cvt_pk_f32_fp8(v.z, true);  h[10] = (_Float16)t.x; h[11] = (_Float16)t.y;
    t = __builtin_amdgcn_cvt_pk_f32_fp8(v.w, false); h[12] = (_Float16)t.x; h[13] = (_Float16)t.y;
    t = __builtin_amdgcn_cvt_pk_f32_fp8(v.w, true);  h[14] = (_Float16)t.x; h[15] = (_Float16)t.y;
    *(uint4*)&a_s[row * KP + cc]     = *(uint4*)&h[0];
    *(uint4*)&a_s[row * KP + cc + 8] = *(uint4*)&h[8];
  }
  f32x4 acc[4][CTW];
#pragma unroll
  for (int rt = 0; rt < 4; ++rt)
#pragma unroll
    for (int ct = 0; ct < CTW; ++ct) acc[rt][ct] = (f32x4){0.f, 0.f, 0.f, 0.f};

  for (int kc = 0; kc < K; kc += KC) {
    __syncthreads();
    for (int idx = tid; idx < M * (KC / 8); idx += 256) {
      int m = idx / (KC / 8), cc = (idx % (KC / 8)) * 8;
      uint4 v = *(const uint4*)(Wt + (size_t)m * K + kc + cc);
      *(uint4*)&w_s[m * WP + cc] = v;
    }
    __syncthreads();
    f16x8 bfr[CTW];
#pragma unroll
    for (int ct = 0; ct < CTW; ++ct)
      bfr[ct] = *(const f16x8*)&w_s[(wave * (M / 4) + ct * 16 + m16) * WP + q * 8];
#pragma unroll
    for (int rt = 0; rt < 4; ++rt) {
      f16x8 afr = *(const f16x8*)&a_s[(rt * 16 + m16) * KP + kc + q * 8];
#pragma unroll
      for (int ct = 0; ct < CTW; ++ct)
        acc[rt][ct] = __builtin_amdgcn_mfma_f32_16x16x32_f16(afr, bfr[ct], acc[rt][ct], 0, 0, 0);
    }
  }

  const int rlast = (r0 + 63 < NN) ? r0 + 63 : NN - 1;
  const int bmin = a.batch[r0];
  const int bmax = a.batch[rlast];
  int rowb[4][4];
#pragma unroll
  for (int rt = 0; rt < 4; ++rt)
#pragma unroll
    for (int reg = 0; reg < 4; ++reg) {
      const int row = r0 + rt * 16 + q * 4 + reg;
      rowb[rt][reg] = (row < NN) ? a.batch[row] : -1;
    }
#pragma unroll
  for (int ct = 0; ct < CTW; ++ct) {
    const int col = wave * (M / 4) + ct * 16 + m16;
    const float bv = bias[col];
    for (int b = bmin; b <= bmax; ++b) {
      float s = 0.f;
#pragma unroll
      for (int rt = 0; rt < 4; ++rt)
#pragma unroll
        for (int reg = 0; reg < 4; ++reg)
          if (rowb[rt][reg] == b) s += fmaxf(acc[rt][ct][reg] + bv, 0.f);
      s += __shfl_xor(s, 16);
      s += __shfl_xor(s, 32);
      if (q == 0) atomAdd(&a.pooled[b * M + col], s);
    }
  }
}

// ---- MLP head + log_softmax ----
__global__ __launch_bounds__(256) void kw_mlp(MegaArgs a) {
  __shared__ float p[256];
  __shared__ float h1[100];
  __shared__ float lo[10];
  const int tid = threadIdx.x;
  const int b = blockIdx.x;
  const float inv = 1.0f / fmaxf(a.pcnt[b], 1.0f);
  p[tid] = a.pooled[b * 256 + tid] * inv;
  __syncthreads();
  for (int j = tid; j < 100; j += 256) {
    float s = a.fc1b[j];
    for (int k = 0; k < 256; ++k) s += p[k] * a.fc1w[k * 100 + j];
    h1[j] = fmaxf(s, 0.f);
  }
  __syncthreads();
  if (tid < 10) {
    float s = a.fc2b[tid];
    for (int k = 0; k < 100; ++k) s += h1[k] * a.fc2w[k * 10 + tid];
    lo[tid] = s;
  }
  __syncthreads();
  if (tid == 0) {
    float m = lo[0];
    for (int j = 1; j < 10; ++j) m = fmaxf(m, lo[j]);
    float ssum = 0.f;
    for (int j = 0; j < 10; ++j) ssum += expf(lo[j] - m);
    float lse = m + logf(ssum);
    for (int j = 0; j < 10; ++j) a.out[b * 10 + j] = lo[j] - lse;
  }
}

extern "C" void kernel_launch(void* const* d_in, const int* in_sizes, int n_in,
                              void* d_out, int out_size, void* d_ws, size_t ws_size,
                              hipStream_t stream) {
  const float* x     = (const float*)d_in[0];
  const int*   ei    = (const int*)d_in[1];
  const int*   batch = (const int*)d_in[2];
  const float* W1 = (const float*)d_in[3];  const float* b1 = (const float*)d_in[4];
  const float* W2 = (const float*)d_in[5];  const float* b2 = (const float*)d_in[6];
  const float* W3 = (const float*)d_in[7];  const float* b3 = (const float*)d_in[8];
  const float* W4 = (const float*)d_in[9];  const float* b4 = (const float*)d_in[10];
  const float* fc1w = (const float*)d_in[11]; const float* fc1b = (const float*)d_in[12];
  const float* fc2w = (const float*)d_in[13]; const float* fc2b = (const float*)d_in[14];
  float* out = (float*)d_out;

  const int* src = ei;
  const int* dst = ei + NE;

  // ---- workspace layout: pcnt|bucketCnt first (tiny memset); pooled zeroed in kw_gather128 ----
  float* ws = (float*)d_ws;
  float* pcnt      = ws;                       // 64
  int*   bucketCnt = (int*)(pcnt + 64);        // 512
  float* pooled = (float*)(bucketCnt + 512);   // 16384
  float* dinv   = pooled + 16384;              // 100352
  int*   rowbeg = (int*)(dinv + 100352);       // 100352
  int*   rowend = rowbeg + 100352;             // 100352
  int*   csrc   = rowend + 100352;             // NPAD
  unsigned* pairs = (unsigned*)(csrc + NPAD);  // NPAD (packed u32)
  _Float16* xs8 = (_Float16*)(pairs + NPAD);   // NN*8 halfs (pad 800768)
  unsigned char* F0 = (unsigned char*)(xs8 + 800768);  // NN*32 bytes (fp8)
  unsigned char* F1 = F0 + 3200000;                    // NN*64 bytes (fp8)
  unsigned char* F2 = F1 + 6400000;                    // NN*128 bytes (fp8)
  unsigned char* AG8 = F2 + 12800000;                  // NN*128 bytes (fp8)
  _Float16* Wt2 = (_Float16*)(AG8 + 12800000); // 32*64
  _Float16* Wt3 = Wt2 + 32 * 64;               // 64*128
  _Float16* Wt4 = Wt3 + 64 * 128;              // 128*256

  // ---- CSR build (tiny memset + 2 kernels) ----
  (void)hipMemsetAsync(ws, 0, (64 + 512) * sizeof(float), stream);
  k_bin<<<(NE + 4095) / 4096, 256, 0, stream>>>(src, dst, bucketCnt, pairs,
                                                W2, W3, W4, Wt2, Wt3, Wt4);
  k_cntfill<<<NB, 256, 0, stream>>>(pairs, bucketCnt, batch, x,
                                    rowbeg, rowend, dinv, csrc, pcnt, xs8);

  // ---- compute phases (9 dispatches; small-K layers fused gather+GEMM) ----
  MegaArgs m;
  m.xs8 = xs8; m.rowbeg = rowbeg; m.rowend = rowend; m.csrc = csrc;
  m.dinv = dinv;
  m.W1 = W1; m.b1 = b1; m.F0 = F0;
  m.Wt2 = Wt2; m.b2 = b2; m.F1 = F1;
  m.Wt3 = Wt3; m.b3 = b3; m.F2 = F2;
  m.Wt4 = Wt4; m.b4 = b4; m.AG8 = AG8;
  m.batch = batch; m.pooled = pooled; m.pcnt = pcnt;
  m.fc1w = fc1w; m.fc1b = fc1b; m.fc2w = fc2w; m.fc2b = fc2b;
  m.out = out;

  kw_l1<<<(NN + 255) / 256, 256, 0, stream>>>(m);
  kw_fused<32, 64><<<(NN + 63) / 64, 256, 0, stream>>>(F0, m, Wt2, b2, F1);
  kw_fused<64, 128><<<(NN + 63) / 64, 256, 0, stream>>>(F1, m, Wt3, b3, F2);
  kw_gather128<<<(NN + 31) / 32, 256, 0, stream>>>(F2, m);
  kw_gemm4<<<(NN + 63) / 64, 256, 0, stream>>>(m, Wt4, b4);
  kw_mlp<<<NBATCH, 256, 0, stream>>>(m);
}

// Round 18
// 280.027 us; speedup vs baseline: 1.0132x; 1.0132x over previous
//
#include <hip/hip_runtime.h>
#include <hip/hip_bf16.h>
#include <cmath>

#define NN 100000
#define NE 1600000
#define NBATCH 64
#define NB 391        // buckets of 256 nodes (dst>>8)
#define NBP 512       // padded bucket count
#define BCAP 5120     // fixed bucket capacity (mean 4096, sigma ~64 -> +16 sigma)
#define NPAD (NB * BCAP)

typedef __attribute__((ext_vector_type(8))) _Float16 f16x8;
typedef __attribute__((ext_vector_type(4))) float f32x4;
typedef __attribute__((ext_vector_type(2))) float f32x2;

__device__ __forceinline__ void atomAdd(float* p, float v) {
  unsafeAtomicAdd(p, v);
}

__device__ __forceinline__ unsigned char f2fp8(float f) {
  int pk = __builtin_amdgcn_cvt_pk_fp8_f32(f, f, 0, false);
  return (unsigned char)(pk & 0xff);
}

__device__ __forceinline__ void fp8x16_to_f16(uint4 v, _Float16* h) {
  f32x2 t;
  t = __builtin_amdgcn_cvt_pk_f32_fp8(v.x, false); h[0] = (_Float16)t.x;  h[1] = (_Float16)t.y;
  t = __builtin_amdgcn_cvt_pk_f32_fp8(v.x, true);  h[2] = (_Float16)t.x;  h[3] = (_Float16)t.y;
  t = __builtin_amdgcn_cvt_pk_f32_fp8(v.y, false); h[4] = (_Float16)t.x;  h[5] = (_Float16)t.y;
  t = __builtin_amdgcn_cvt_pk_f32_fp8(v.y, true);  h[6] = (_Float16)t.x;  h[7] = (_Float16)t.y;
  t = __builtin_amdgcn_cvt_pk_f32_fp8(v.z, false); h[8] = (_Float16)t.x;  h[9] = (_Float16)t.y;
  t = __builtin_amdgcn_cvt_pk_f32_fp8(v.z, true);  h[10] = (_Float16)t.x; h[11] = (_Float16)t.y;
  t = __builtin_amdgcn_cvt_pk_f32_fp8(v.w, false); h[12] = (_Float16)t.x; h[13] = (_Float16)t.y;
  t = __builtin_amdgcn_cvt_pk_f32_fp8(v.w, true);  h[14] = (_Float16)t.x; h[15] = (_Float16)t.y;
}

// ---- bin edges into fixed-capacity bucket regions (LDS counting sort / 4096-chunk) ----
__global__ __launch_bounds__(256) void k_bin(const int* __restrict__ src,
    const int* __restrict__ dst, int* __restrict__ bucketCnt, unsigned* __restrict__ pairs,
    const float* __restrict__ W2, const float* __restrict__ W3, const float* __restrict__ W4,
    _Float16* __restrict__ Wt2, _Float16* __restrict__ Wt3, _Float16* __restrict__ Wt4) {
  __shared__ int hist[NBP];
  __shared__ int scn[NBP];
  __shared__ int ofs[NBP];
  __shared__ int gbase[NBP];
  __shared__ unsigned buf[4096];
  __shared__ unsigned short bufb[4096];
  const int base = blockIdx.x * 4096;
  const int n = (NE - base < 4096) ? NE - base : 4096;
  for (int i = threadIdx.x; i < NBP; i += 256) hist[i] = 0;
  __syncthreads();

  int myS[16], myD[16];
  int nloc = 0;
  for (int i = threadIdx.x, j = 0; i < n; i += 256, ++j) {
    myS[j] = src[base + i];
    myD[j] = dst[base + i];
    atomicAdd(&hist[myD[j] >> 8], 1);
    nloc = j + 1;
  }
  __syncthreads();

  scn[threadIdx.x] = hist[threadIdx.x];
  scn[threadIdx.x + 256] = hist[threadIdx.x + 256];
  __syncthreads();
  for (int off = 1; off < NBP; off <<= 1) {
    const int i0 = threadIdx.x, i1 = threadIdx.x + 256;
    int t0 = (i0 >= off) ? scn[i0 - off] : 0;
    int t1 = (i1 >= off) ? scn[i1 - off] : 0;
    __syncthreads();
    scn[i0] += t0;
    scn[i1] += t1;
    __syncthreads();
  }
  ofs[threadIdx.x] = scn[threadIdx.x] - hist[threadIdx.x];
  ofs[threadIdx.x + 256] = scn[threadIdx.x + 256] - hist[threadIdx.x + 256];
  for (int b = threadIdx.x; b < NB; b += 256) {
    int c = hist[b];
    if (c) gbase[b] = b * BCAP + atomicAdd(&bucketCnt[b], c);
  }
  __syncthreads();

  for (int j = 0; j < nloc; ++j) {
    int b = myD[j] >> 8;
    int slot = atomicAdd(&ofs[b], 1);
    buf[slot] = ((unsigned)myS[j] << 8) | ((unsigned)myD[j] & 255u);
    bufb[slot] = (unsigned short)b;
  }
  __syncthreads();

  for (int i = threadIdx.x; i < n; i += 256) {
    int b = (int)bufb[i];
    int ex = scn[b] - hist[b];
    pairs[gbase[b] + (i - ex)] = buf[i];
  }

  int idx = blockIdx.x * 256 + threadIdx.x;
  if (idx < 2048) {
    int k = idx / 64, m = idx - k * 64;
    Wt2[m * 32 + k] = (_Float16)W2[idx];
  } else if (idx < 10240) {
    int j = idx - 2048;
    int k = j / 128, m = j - k * 128;
    Wt3[m * 64 + k] = (_Float16)W3[j];
  } else if (idx < 43008) {
    int j = idx - 10240;
    int k = j / 256, m = j - k * 256;
    Wt4[m * 128 + k] = (_Float16)W4[j];
  }
}

// ---- per-bucket: count + local scan -> rowbeg/rowend/dinv + csrc fill + batch hist + xs8 pack ----
__global__ __launch_bounds__(256) void k_cntfill(const unsigned* __restrict__ pairs,
    const int* __restrict__ bucketCnt, const int* __restrict__ batch,
    const float* __restrict__ x, int* __restrict__ rowbeg, int* __restrict__ rowend,
    float* __restrict__ dinv, int* __restrict__ csrc, float* __restrict__ pcnt,
    _Float16* __restrict__ xs8) {
  __shared__ int c[256];
  __shared__ int scn[256];
  __shared__ int rowb[256];
  __shared__ int ofs[256];
  __shared__ int h[64];
  const int tid = threadIdx.x;
  c[tid] = 0; ofs[tid] = 0;
  if (tid < 64) h[tid] = 0;
  __syncthreads();
  const int b = blockIdx.x;
  const int s = b * BCAP;
  const int e = s + bucketCnt[b];
  for (int i = s + tid; i < e; i += 256) atomicAdd(&c[pairs[i] & 255u], 1);
  __syncthreads();
  const int v = c[tid];
  scn[tid] = v;
  __syncthreads();
  for (int off = 1; off < 256; off <<= 1) {
    int t = (tid >= off) ? scn[tid - off] : 0;
    __syncthreads();
    scn[tid] += t;
    __syncthreads();
  }
  rowb[tid] = s + scn[tid] - v;
  const int node = b * 256 + tid;
  rowbeg[node] = rowb[tid];
  rowend[node] = rowb[tid] + v;
  if (node < NN) {
    const float di = rsqrtf((float)v + 1.0f);
    dinv[node] = di;
    f16x8 o = {0, 0, 0, 0, 0, 0, 0, 0};
    o[0] = (_Float16)(x[(size_t)node * 5 + 0] * di);
    o[1] = (_Float16)(x[(size_t)node * 5 + 1] * di);
    o[2] = (_Float16)(x[(size_t)node * 5 + 2] * di);
    o[3] = (_Float16)(x[(size_t)node * 5 + 3] * di);
    o[4] = (_Float16)(x[(size_t)node * 5 + 4] * di);
    *(f16x8*)(xs8 + (size_t)node * 8) = o;
    atomicAdd(&h[batch[node]], 1);
  }
  __syncthreads();
  for (int i = s + tid; i < e; i += 256) {
    unsigned p = pairs[i];
    int t = (int)(p & 255u);
    int pos = rowb[t] + atomicAdd(&ofs[t], 1);
    csrc[pos] = (int)(p >> 8);
  }
  if (tid < 64 && h[tid]) atomAdd(&pcnt[tid], (float)h[tid]);
}

// ================== phase args ==================
struct MegaArgs {
  const _Float16* xs8;
  const int* rowbeg; const int* rowend; const int* csrc;
  const float* dinv;
  const float* W1; const float* b1;
  unsigned char* F0;
  const _Float16* Wt2; const float* b2;
  unsigned char* F1;
  const _Float16* Wt3; const float* b3;
  unsigned char* F2;
  const _Float16* Wt4; const float* b4;
  unsigned char* AG8;
  const int* batch; float* pooled; const float* pcnt;
  const float* fc1w; const float* fc1b; const float* fc2w; const float* fc2b;
  float* out;
};

// ---- layer1: fp16 xs8 gather + 5->32 GEMM, fp8 out (pre-scaled) ----
__global__ __launch_bounds__(256) void kw_l1(MegaArgs a) {
  __shared__ float w_s[160];
  __shared__ float b_s[32];
  const int tid = threadIdx.x;
  if (tid < 160) w_s[tid] = a.W1[tid];
  if (tid < 32) b_s[tid] = a.b1[tid];
  __syncthreads();
  const int r = blockIdx.x * 256 + tid;
  if (r >= NN) return;
  const float di = a.dinv[r];
  f16x8 av = *(const f16x8*)(a.xs8 + (size_t)r * 8);
  f16x8 cacc = {0, 0, 0, 0, 0, 0, 0, 0};
  int e = a.rowbeg[r];
  const int e1 = a.rowend[r];
  for (; e + 2 <= e1; e += 2) {
    const int s0 = a.csrc[e], s1 = a.csrc[e + 1];
    av   += *(const f16x8*)(a.xs8 + (size_t)s0 * 8);
    cacc += *(const f16x8*)(a.xs8 + (size_t)s1 * 8);
  }
  if (e < e1) av += *(const f16x8*)(a.xs8 + (size_t)a.csrc[e] * 8);
  av += cacc;
  const float f0 = (float)av[0] * di, f1 = (float)av[1] * di, f2 = (float)av[2] * di,
              f3 = (float)av[3] * di, f4 = (float)av[4] * di;
  float v[32];
#pragma unroll
  for (int j = 0; j < 32; ++j) {
    float s = b_s[j] + f0 * w_s[j] + f1 * w_s[32 + j] + f2 * w_s[64 + j]
                     + f3 * w_s[96 + j] + f4 * w_s[128 + j];
    v[j] = fmaxf(s, 0.f) * di;
  }
  unsigned u[8];
#pragma unroll
  for (int g2 = 0; g2 < 8; ++g2) {
    int uu = 0;
    uu = __builtin_amdgcn_cvt_pk_fp8_f32(v[4 * g2],     v[4 * g2 + 1], uu, false);
    uu = __builtin_amdgcn_cvt_pk_fp8_f32(v[4 * g2 + 2], v[4 * g2 + 3], uu, true);
    u[g2] = (unsigned)uu;
  }
  uint4* op = (uint4*)(a.F0 + (size_t)r * 32);
  op[0] = make_uint4(u[0], u[1], u[2], u[3]);
  op[1] = make_uint4(u[4], u[5], u[6], u[7]);
}

// ---- fp8 CSR gather -> fp8 AG (pre-scaled by dinv) ----
template<int K>
__global__ __launch_bounds__(256) void kw_gather8(const unsigned char* __restrict__ in,
    MegaArgs a) {
  constexpr int TPR = K / 16;
  constexpr int RPB = 256 / TPR;
  const int r = blockIdx.x * RPB + threadIdx.x / TPR;
  if (r >= NN) return;
  const int c = (threadIdx.x % TPR) * 16;
  const float di = a.dinv[r];
  f32x2 acc[8];
  {
    const uint4 v = *(const uint4*)(in + (size_t)r * K + c);
    acc[0] = __builtin_amdgcn_cvt_pk_f32_fp8(v.x, false);
    acc[1] = __builtin_amdgcn_cvt_pk_f32_fp8(v.x, true);
    acc[2] = __builtin_amdgcn_cvt_pk_f32_fp8(v.y, false);
    acc[3] = __builtin_amdgcn_cvt_pk_f32_fp8(v.y, true);
    acc[4] = __builtin_amdgcn_cvt_pk_f32_fp8(v.z, false);
    acc[5] = __builtin_amdgcn_cvt_pk_f32_fp8(v.z, true);
    acc[6] = __builtin_amdgcn_cvt_pk_f32_fp8(v.w, false);
    acc[7] = __builtin_amdgcn_cvt_pk_f32_fp8(v.w, true);
  }
  int e = a.rowbeg[r];
  const int e1 = a.rowend[r];
  for (; e + 2 <= e1; e += 2) {
    const int s0 = a.csrc[e], s1 = a.csrc[e + 1];
    const uint4 v0 = *(const uint4*)(in + (size_t)s0 * K + c);
    const uint4 v1 = *(const uint4*)(in + (size_t)s1 * K + c);
    acc[0] += __builtin_amdgcn_cvt_pk_f32_fp8(v0.x, false);
    acc[1] += __builtin_amdgcn_cvt_pk_f32_fp8(v0.x, true);
    acc[2] += __builtin_amdgcn_cvt_pk_f32_fp8(v0.y, false);
    acc[3] += __builtin_amdgcn_cvt_pk_f32_fp8(v0.y, true);
    acc[4] += __builtin_amdgcn_cvt_pk_f32_fp8(v0.z, false);
    acc[5] += __builtin_amdgcn_cvt_pk_f32_fp8(v0.z, true);
    acc[6] += __builtin_amdgcn_cvt_pk_f32_fp8(v0.w, false);
    acc[7] += __builtin_amdgcn_cvt_pk_f32_fp8(v0.w, true);
    acc[0] += __builtin_amdgcn_cvt_pk_f32_fp8(v1.x, false);
    acc[1] += __builtin_amdgcn_cvt_pk_f32_fp8(v1.x, true);
    acc[2] += __builtin_amdgcn_cvt_pk_f32_fp8(v1.y, false);
    acc[3] += __builtin_amdgcn_cvt_pk_f32_fp8(v1.y, true);
    acc[4] += __builtin_amdgcn_cvt_pk_f32_fp8(v1.z, false);
    acc[5] += __builtin_amdgcn_cvt_pk_f32_fp8(v1.z, true);
    acc[6] += __builtin_amdgcn_cvt_pk_f32_fp8(v1.w, false);
    acc[7] += __builtin_amdgcn_cvt_pk_f32_fp8(v1.w, true);
  }
  if (e < e1) {
    const uint4 v0 = *(const uint4*)(in + (size_t)a.csrc[e] * K + c);
    acc[0] += __builtin_amdgcn_cvt_pk_f32_fp8(v0.x, false);
    acc[1] += __builtin_amdgcn_cvt_pk_f32_fp8(v0.x, true);
    acc[2] += __builtin_amdgcn_cvt_pk_f32_fp8(v0.y, false);
    acc[3] += __builtin_amdgcn_cvt_pk_f32_fp8(v0.y, true);
    acc[4] += __builtin_amdgcn_cvt_pk_f32_fp8(v0.z, false);
    acc[5] += __builtin_amdgcn_cvt_pk_f32_fp8(v0.z, true);
    acc[6] += __builtin_amdgcn_cvt_pk_f32_fp8(v0.w, false);
    acc[7] += __builtin_amdgcn_cvt_pk_f32_fp8(v0.w, true);
  }
  int w0 = 0, w1 = 0, w2 = 0, w3 = 0;
  w0 = __builtin_amdgcn_cvt_pk_fp8_f32(acc[0].x * di, acc[0].y * di, 0, false);
  w0 = __builtin_amdgcn_cvt_pk_fp8_f32(acc[1].x * di, acc[1].y * di, w0, true);
  w1 = __builtin_amdgcn_cvt_pk_fp8_f32(acc[2].x * di, acc[2].y * di, 0, false);
  w1 = __builtin_amdgcn_cvt_pk_fp8_f32(acc[3].x * di, acc[3].y * di, w1, true);
  w2 = __builtin_amdgcn_cvt_pk_fp8_f32(acc[4].x * di, acc[4].y * di, 0, false);
  w2 = __builtin_amdgcn_cvt_pk_fp8_f32(acc[5].x * di, acc[5].y * di, w2, true);
  w3 = __builtin_amdgcn_cvt_pk_fp8_f32(acc[6].x * di, acc[6].y * di, 0, false);
  w3 = __builtin_amdgcn_cvt_pk_fp8_f32(acc[7].x * di, acc[7].y * di, w3, true);
  *(uint4*)(a.AG8 + (size_t)r * K + c) = make_uint4((unsigned)w0, (unsigned)w1,
                                                    (unsigned)w2, (unsigned)w3);
}

// ---- MFMA GEMM (fp8 AG staged to fp16 LDS). MODE 0: fp8 out; MODE 1: fused mean-pool ----
template<int K, int M, int MODE>
__global__ __launch_bounds__(256) void kw_gemm(MegaArgs a,
    const _Float16* __restrict__ Wt, const float* __restrict__ bias,
    unsigned char* __restrict__ outp) {
  constexpr int KC = 32;          // one 16x16x32 MFMA consumes 32 k's per chunk
  constexpr int KP = K + 8;
  constexpr int WP = KC + 8;
  constexpr int CTW = M / 64;
  constexpr int C16 = K / 16;
  __shared__ _Float16 a_s[64 * KP];
  __shared__ _Float16 w_s[M * WP];
  const int tid = threadIdx.x;
  const int wave = tid >> 6, lane = tid & 63;
  const int m16 = lane & 15, q = lane >> 4;
  const int r0 = blockIdx.x * 64;

  for (int idx = tid; idx < 64 * C16; idx += 256) {
    int row = idx / C16, cc = (idx % C16) * 16;
    uint4 v = {0u, 0u, 0u, 0u};
    if (r0 + row < NN) v = *(const uint4*)(a.AG8 + (size_t)(r0 + row) * K + cc);
    _Float16 h[16];
    fp8x16_to_f16(v, h);
    *(uint4*)&a_s[row * KP + cc]     = *(uint4*)&h[0];
    *(uint4*)&a_s[row * KP + cc + 8] = *(uint4*)&h[8];
  }
  f32x4 acc[4][CTW];
#pragma unroll
  for (int rt = 0; rt < 4; ++rt)
#pragma unroll
    for (int ct = 0; ct < CTW; ++ct) acc[rt][ct] = (f32x4){0.f, 0.f, 0.f, 0.f};

  for (int kc = 0; kc < K; kc += KC) {
    __syncthreads();
    for (int idx = tid; idx < M * (KC / 8); idx += 256) {
      int m = idx / (KC / 8), cc = (idx % (KC / 8)) * 8;
      uint4 v = *(const uint4*)(Wt + (size_t)m * K + kc + cc);
      *(uint4*)&w_s[m * WP + cc] = v;
    }
    __syncthreads();
    f16x8 bfr[CTW];
#pragma unroll
    for (int ct = 0; ct < CTW; ++ct)
      bfr[ct] = *(const f16x8*)&w_s[(wave * (M / 4) + ct * 16 + m16) * WP + q * 8];
#pragma unroll
    for (int rt = 0; rt < 4; ++rt) {
      f16x8 afr = *(const f16x8*)&a_s[(rt * 16 + m16) * KP + kc + q * 8];
#pragma unroll
      for (int ct = 0; ct < CTW; ++ct)
        acc[rt][ct] = __builtin_amdgcn_mfma_f32_16x16x32_f16(afr, bfr[ct], acc[rt][ct], 0, 0, 0);
    }
  }

  if constexpr (MODE == 1) {
    const int rlast = (r0 + 63 < NN) ? r0 + 63 : NN - 1;
    const int bmin = a.batch[r0];
    const int bmax = a.batch[rlast];
    int rowb[4][4];
#pragma unroll
    for (int rt = 0; rt < 4; ++rt)
#pragma unroll
      for (int reg = 0; reg < 4; ++reg) {
        const int row = r0 + rt * 16 + q * 4 + reg;
        rowb[rt][reg] = (row < NN) ? a.batch[row] : -1;
      }
#pragma unroll
    for (int ct = 0; ct < CTW; ++ct) {
      const int col = wave * (M / 4) + ct * 16 + m16;
      const float bv = bias[col];
      for (int b = bmin; b <= bmax; ++b) {
        float s = 0.f;
#pragma unroll
        for (int rt = 0; rt < 4; ++rt)
#pragma unroll
          for (int reg = 0; reg < 4; ++reg)
            if (rowb[rt][reg] == b) s += fmaxf(acc[rt][ct][reg] + bv, 0.f);
        s += __shfl_xor(s, 16);
        s += __shfl_xor(s, 32);
        if (q == 0) atomAdd(&a.pooled[b * M + col], s);
      }
    }
  } else {
    float dsc[4][4];
#pragma unroll
    for (int rt = 0; rt < 4; ++rt)
#pragma unroll
      for (int reg = 0; reg < 4; ++reg) {
        const int row = r0 + rt * 16 + q * 4 + reg;
        dsc[rt][reg] = (row < NN) ? a.dinv[row] : 0.f;
      }
#pragma unroll
    for (int rt = 0; rt < 4; ++rt) {
#pragma unroll
      for (int ct = 0; ct < CTW; ++ct) {
        const int col = wave * (M / 4) + ct * 16 + m16;
        const float bv = bias[col];
#pragma unroll
        for (int reg = 0; reg < 4; ++reg) {
          const int row = r0 + rt * 16 + q * 4 + reg;
          if (row < NN) {
            float vv = fmaxf(acc[rt][ct][reg] + bv, 0.f) * dsc[rt][reg];
            outp[(size_t)row * M + col] = f2fp8(vv);
          }
        }
      }
    }
  }
}

// ---- MLP head + log_softmax ----
__global__ __launch_bounds__(256) void kw_mlp(MegaArgs a) {
  __shared__ float p[256];
  __shared__ float h1[100];
  __shared__ float lo[10];
  const int tid = threadIdx.x;
  const int b = blockIdx.x;
  const float inv = 1.0f / fmaxf(a.pcnt[b], 1.0f);
  p[tid] = a.pooled[b * 256 + tid] * inv;
  __syncthreads();
  for (int j = tid; j < 100; j += 256) {
    float s = a.fc1b[j];
    for (int k = 0; k < 256; ++k) s += p[k] * a.fc1w[k * 100 + j];
    h1[j] = fmaxf(s, 0.f);
  }
  __syncthreads();
  if (tid < 10) {
    float s = a.fc2b[tid];
    for (int k = 0; k < 100; ++k) s += h1[k] * a.fc2w[k * 10 + tid];
    lo[tid] = s;
  }
  __syncthreads();
  if (tid == 0) {
    float m = lo[0];
    for (int j = 1; j < 10; ++j) m = fmaxf(m, lo[j]);
    float ssum = 0.f;
    for (int j = 0; j < 10; ++j) ssum += expf(lo[j] - m);
    float lse = m + logf(ssum);
    for (int j = 0; j < 10; ++j) a.out[b * 10 + j] = lo[j] - lse;
  }
}

extern "C" void kernel_launch(void* const* d_in, const int* in_sizes, int n_in,
                              void* d_out, int out_size, void* d_ws, size_t ws_size,
                              hipStream_t stream) {
  const float* x     = (const float*)d_in[0];
  const int*   ei    = (const int*)d_in[1];
  const int*   batch = (const int*)d_in[2];
  const float* W1 = (const float*)d_in[3];  const float* b1 = (const float*)d_in[4];
  const float* W2 = (const float*)d_in[5];  const float* b2 = (const float*)d_in[6];
  const float* W3 = (const float*)d_in[7];  const float* b3 = (const float*)d_in[8];
  const float* W4 = (const float*)d_in[9];  const float* b4 = (const float*)d_in[10];
  const float* fc1w = (const float*)d_in[11]; const float* fc1b = (const float*)d_in[12];
  const float* fc2w = (const float*)d_in[13]; const float* fc2b = (const float*)d_in[14];
  float* out = (float*)d_out;

  const int* src = ei;
  const int* dst = ei + NE;

  // ---- workspace layout (pooled|pcnt|bucketCnt adjacent -> single memset) ----
  float* ws = (float*)d_ws;
  float* pooled = ws;                          // 16384
  float* pcnt   = pooled + 16384;              // 64
  int*   bucketCnt = (int*)(pcnt + 64);        // 512
  float* dinv   = (float*)(bucketCnt + 512);   // 100352
  int*   rowbeg = (int*)(dinv + 100352);       // 100352
  int*   rowend = rowbeg + 100352;             // 100352
  int*   csrc   = rowend + 100352;             // NPAD
  unsigned* pairs = (unsigned*)(csrc + NPAD);  // NPAD (packed u32)
  _Float16* xs8 = (_Float16*)(pairs + NPAD);   // NN*8 halfs (pad 800768)
  unsigned char* F0 = (unsigned char*)(xs8 + 800768);  // NN*32 bytes (fp8)
  unsigned char* F1 = F0 + 3200000;                    // NN*64 bytes (fp8)
  unsigned char* F2 = F1 + 6400000;                    // NN*128 bytes (fp8)
  unsigned char* AG8 = F2 + 12800000;                  // NN*128 bytes (fp8)
  _Float16* Wt2 = (_Float16*)(AG8 + 12800000); // 32*64
  _Float16* Wt3 = Wt2 + 32 * 64;               // 64*128
  _Float16* Wt4 = Wt3 + 64 * 128;              // 128*256

  // ---- CSR build (memset + 2 kernels) ----
  (void)hipMemsetAsync(pooled, 0, (16384 + 64 + 512) * sizeof(float), stream);
  k_bin<<<(NE + 4095) / 4096, 256, 0, stream>>>(src, dst, bucketCnt, pairs,
                                                W2, W3, W4, Wt2, Wt3, Wt4);
  k_cntfill<<<NB, 256, 0, stream>>>(pairs, bucketCnt, batch, x,
                                    rowbeg, rowend, dinv, csrc, pcnt, xs8);

  // ---- compute phases (discrete launches; dispatch boundaries are the cheap barrier) ----
  MegaArgs m;
  m.xs8 = xs8; m.rowbeg = rowbeg; m.rowend = rowend; m.csrc = csrc;
  m.dinv = dinv;
  m.W1 = W1; m.b1 = b1; m.F0 = F0;
  m.Wt2 = Wt2; m.b2 = b2; m.F1 = F1;
  m.Wt3 = Wt3; m.b3 = b3; m.F2 = F2;
  m.Wt4 = Wt4; m.b4 = b4; m.AG8 = AG8;
  m.batch = batch; m.pooled = pooled; m.pcnt = pcnt;
  m.fc1w = fc1w; m.fc1b = fc1b; m.fc2w = fc2w; m.fc2b = fc2b;
  m.out = out;

  kw_l1<<<(NN + 255) / 256, 256, 0, stream>>>(m);
  kw_gather8<32><<<(NN + 127) / 128, 256, 0, stream>>>(F0, m);
  kw_gemm<32, 64, 0><<<(NN + 63) / 64, 256, 0, stream>>>(m, Wt2, b2, F1);
  kw_gather8<64><<<(NN + 63) / 64, 256, 0, stream>>>(F1, m);
  kw_gemm<64, 128, 0><<<(NN + 63) / 64, 256, 0, stream>>>(m, Wt3, b3, F2);
  kw_gather8<128><<<(NN + 31) / 32, 256, 0, stream>>>(F2, m);
  kw_gemm<128, 256, 1><<<(NN + 63) / 64, 256, 0, stream>>>(m, Wt4, b4, nullptr);
  kw_mlp<<<NBATCH, 256, 0, stream>>>(m);
}